// Round 1
// baseline (559.244 us; speedup 1.0000x reference)
//
#include <hip/hip_runtime.h>
#include <math.h>

#define NBANDS 5
#define BATCH  512
#define NPG    62
#define NTOT   (BATCH*NPG)     // 31744
#define F_IN   5
#define NH     8
#define NC     3
#define HC     (NH*NC)         // 24
#define EG     (NPG*16)        // 992 edges per graph
#define ETOT   (BATCH*EG)      // 507904
#define EPG    (EG+NPG)        // 1054 incl self loops
#define DE_DIM 930

// workspace layout (floats)
#define WS_BN     0                    // 5 bands * 10 (sum[5], sumsq[5])
#define WS_POOLED 64                   // 5*512*3 = 7680
#define WS_Q      (WS_POOLED + NBANDS*BATCH*NC)
#define WS_K      (WS_Q + BATCH*64)
#define WS_V      (WS_K + BATCH*64)
// total = 64 + 7680 + 3*32768 = 106048 floats (~424 KB)

__device__ __forceinline__ float eluf(float x) { return x > 0.f ? x : expm1f(x); }

// ---------------- kernel A: BN batch stats (partial sums, global atomics) ----
__global__ __launch_bounds__(256) void bn_stats(const float* __restrict__ x,
                                                float* __restrict__ ws) {
    int band = blockIdx.x;
    int chunk = blockIdx.y;                 // 8 chunks
    const int ROWS = NTOT / 8;              // 3968
    int r0 = chunk * ROWS;
    const float* xb = x + (size_t)band * NTOT * F_IN;
    float s[F_IN] = {0,0,0,0,0}, q[F_IN] = {0,0,0,0,0};
    for (int r = r0 + threadIdx.x; r < r0 + ROWS; r += 256) {
        const float* row = xb + (size_t)r * F_IN;
        #pragma unroll
        for (int f = 0; f < F_IN; ++f) { float v = row[f]; s[f] += v; q[f] += v * v; }
    }
    #pragma unroll
    for (int f = 0; f < F_IN; ++f) {
        for (int off = 32; off; off >>= 1) {
            s[f] += __shfl_down(s[f], off, 64);
            q[f] += __shfl_down(q[f], off, 64);
        }
    }
    if ((threadIdx.x & 63) == 0) {
        float* dst = ws + band * 10;
        #pragma unroll
        for (int f = 0; f < F_IN; ++f) {
            atomicAdd(&dst[f], s[f]);
            atomicAdd(&dst[5 + f], q[f]);
        }
    }
}

// ---------------- kernel B: per-(band,graph) GAT + mean pool ---------------
__global__ __launch_bounds__(256) void gat_kernel(
    const float* __restrict__ x, const int* __restrict__ ei,
    const float* __restrict__ bn_g, const float* __restrict__ bn_b,
    const float* __restrict__ Wg, const float* __restrict__ attSg,
    const float* __restrict__ attDg, const float* __restrict__ biasg,
    const float* __restrict__ ws_bn, float* __restrict__ pooled) {
    int g    = blockIdx.x;
    int band = blockIdx.y;
    __shared__ float Wl[F_IN * HC];          // 120
    __shared__ float attS[HC], attD[HC];
    __shared__ float xt[NPG * HC];           // 1488
    __shared__ float als[NPG * NH], ald[NPG * NH];  // 496 each
    __shared__ int   epk[EPG];               // 1054
    __shared__ int   mkey[NPG * NH];         // reused as float max after decode
    __shared__ float den[NPG * NH];
    __shared__ float msg[NPG * HC];

    int tid = threadIdx.x;
    int nbase = g * NPG;

    if (tid < F_IN * HC) Wl[tid] = Wg[band * F_IN * HC + tid];
    if (tid >= 128 && tid < 128 + HC) attS[tid - 128] = attSg[band * HC + tid - 128];
    if (tid >= 160 && tid < 160 + HC) attD[tid - 160] = attDg[band * HC + tid - 160];

    const int* srcp = ei + (size_t)band * 2 * ETOT + (size_t)g * EG;
    const int* dstp = srcp + ETOT;
    for (int e = tid; e < EPG; e += 256) {
        int ls, ld;
        if (e < EG) { ls = srcp[e] - nbase; ld = dstp[e] - nbase; }
        else        { ls = ld = e - EG; }
        epk[e] = ls | (ld << 16);
    }
    for (int i = tid; i < NPG * NH; i += 256) { mkey[i] = (int)0x80000000; den[i] = 0.f; }
    for (int i = tid; i < NPG * HC; i += 256) msg[i] = 0.f;
    __syncthreads();

    // per-node: BN-normalize, xt = xn@W, attention logits
    if (tid < NPG) {
        const float* st = ws_bn + band * 10;
        const float* xr = x + (size_t)band * NTOT * F_IN + (size_t)(nbase + tid) * F_IN;
        float xn[F_IN];
        #pragma unroll
        for (int f = 0; f < F_IN; ++f) {
            float mu   = st[f] * (1.0f / NTOT);
            float var  = st[5 + f] * (1.0f / NTOT) - mu * mu;
            float rstd = rsqrtf(var + 1e-5f);
            xn[f] = (xr[f] - mu) * rstd * bn_g[band * F_IN + f] + bn_b[band * F_IN + f];
        }
        float xtv[HC];
        #pragma unroll
        for (int o = 0; o < HC; ++o) {
            float a = 0.f;
            #pragma unroll
            for (int f = 0; f < F_IN; ++f) a += xn[f] * Wl[f * HC + o];
            xtv[o] = a;
            xt[tid * HC + o] = a;
        }
        #pragma unroll
        for (int h = 0; h < NH; ++h) {
            float as = 0.f, ad = 0.f;
            #pragma unroll
            for (int c = 0; c < NC; ++c) {
                as += xtv[h * NC + c] * attS[h * NC + c];
                ad += xtv[h * NC + c] * attD[h * NC + c];
            }
            als[tid * NH + h] = as;
            ald[tid * NH + h] = ad;
        }
    }
    __syncthreads();

    // pass 1: segment max per (dst,h) via LDS atomicMax on order-preserving int key
    for (int it = tid; it < EPG * NH; it += 256) {
        int e = it >> 3, h = it & 7;
        int pk = epk[e]; int ls = pk & 0xffff, ld = pk >> 16;
        float v = als[ls * NH + h] + ald[ld * NH + h];
        v = v > 0.f ? v : 0.2f * v;
        int iv  = __float_as_int(v);
        int key = iv >= 0 ? iv : (iv ^ 0x7fffffff);
        atomicMax(&mkey[ld * NH + h], key);
    }
    __syncthreads();
    for (int i = tid; i < NPG * NH; i += 256) {
        int k = mkey[i];
        ((float*)mkey)[i] = __int_as_float(k >= 0 ? k : (k ^ 0x7fffffff));
    }
    __syncthreads();
    const float* mval = (const float*)mkey;

    // pass 2: exp, denom, messages
    for (int it = tid; it < EPG * NH; it += 256) {
        int e = it >> 3, h = it & 7;
        int pk = epk[e]; int ls = pk & 0xffff, ld = pk >> 16;
        float v = als[ls * NH + h] + ald[ld * NH + h];
        v = v > 0.f ? v : 0.2f * v;
        float ex = __expf(v - mval[ld * NH + h]);
        atomicAdd(&den[ld * NH + h], ex);
        #pragma unroll
        for (int c = 0; c < NC; ++c)
            atomicAdd(&msg[ld * HC + h * NC + c], ex * xt[ls * HC + h * NC + c]);
    }
    __syncthreads();

    // node output (head mean + bias + elu) then graph mean pool
    float oc[NC] = {0.f, 0.f, 0.f};
    if (tid < NPG) {
        #pragma unroll
        for (int c = 0; c < NC; ++c) {
            float a = 0.f;
            #pragma unroll
            for (int h = 0; h < NH; ++h)
                a += msg[tid * HC + h * NC + c] / den[tid * NH + h];
            a = a * (1.0f / NH) + biasg[band * NC + c];
            oc[c] = eluf(a);
        }
    }
    if (tid < 64) {   // wave 0 holds all 62 node threads
        #pragma unroll
        for (int c = 0; c < NC; ++c) {
            float v = oc[c];
            for (int off = 32; off; off >>= 1) v += __shfl_down(v, off, 64);
            if (tid == 0)
                pooled[((size_t)band * BATCH + g) * NC + c] = v * (1.0f / NPG);
        }
    }
}

// ---------------- kernel C1: LayerNorm + Q/K/V projections -----------------
__global__ __launch_bounds__(256) void ln_qkv(
    const float* __restrict__ de, const float* __restrict__ ln_g,
    const float* __restrict__ ln_b,
    const float* __restrict__ qW, const float* __restrict__ qb,
    const float* __restrict__ kW, const float* __restrict__ kb,
    const float* __restrict__ vW, const float* __restrict__ vb,
    float* __restrict__ Q, float* __restrict__ K, float* __restrict__ V) {
    int b = blockIdx.x;
    __shared__ float dn[DE_DIM];
    __shared__ float red[8];
    int tid = threadIdx.x;
    const float* row = de + (size_t)b * DE_DIM;
    float s1 = 0.f, s2 = 0.f;
    for (int i = tid; i < DE_DIM; i += 256) {
        float v = row[i]; dn[i] = v; s1 += v; s2 += v * v;
    }
    for (int off = 32; off; off >>= 1) {
        s1 += __shfl_down(s1, off, 64);
        s2 += __shfl_down(s2, off, 64);
    }
    if ((tid & 63) == 0) { red[tid >> 6] = s1; red[4 + (tid >> 6)] = s2; }
    __syncthreads();
    float mu   = (red[0] + red[1] + red[2] + red[3]) * (1.0f / DE_DIM);
    float var  = (red[4] + red[5] + red[6] + red[7]) * (1.0f / DE_DIM) - mu * mu;
    float rstd = rsqrtf(var + 1e-5f);
    for (int i = tid; i < DE_DIM; i += 256)
        dn[i] = (dn[i] - mu) * rstd * ln_g[i] + ln_b[i];
    __syncthreads();

    if (tid < 192) {
        int m = tid >> 6, col = tid & 63;
        const float* Wm = (m == 0) ? qW : (m == 1) ? kW : vW;
        const float* bm = (m == 0) ? qb : (m == 1) ? kb : vb;
        float acc = 0.f;
        #pragma unroll 5
        for (int i = 0; i < DE_DIM; ++i) acc += dn[i] * Wm[(size_t)i * 64 + col];
        acc += bm[col];
        float* o = (m == 0) ? Q : (m == 1) ? K : V;
        o[(size_t)b * 64 + col] = acc;
    }
}

// ---------------- kernel C2: attention + fusion tail -----------------------
__global__ __launch_bounds__(256) void attn_final(
    const float* __restrict__ Q, const float* __restrict__ K,
    const float* __restrict__ V, const float* __restrict__ pooled,
    const float* __restrict__ fgW, const float* __restrict__ fgb,
    const float* __restrict__ faW, const float* __restrict__ fab,
    float* __restrict__ out) {
    int b = blockIdx.x;
    int tid = threadIdx.x;
    __shared__ float qrow[64];
    __shared__ float p[BATCH];
    __shared__ float red[8];
    __shared__ float pv[4][64];
    __shared__ float xde[64], xout[64];
    if (tid < 64) qrow[tid] = Q[(size_t)b * 64 + tid];
    __syncthreads();

    float sj[2];
    #pragma unroll
    for (int r = 0; r < 2; ++r) {
        int j = tid + r * 256;
        const float4* k4 = (const float4*)(K + (size_t)j * 64);
        float a = 0.f;
        #pragma unroll
        for (int i = 0; i < 16; ++i) {
            float4 kv = k4[i];
            a += qrow[4*i]   * kv.x + qrow[4*i+1] * kv.y
               + qrow[4*i+2] * kv.z + qrow[4*i+3] * kv.w;
        }
        sj[r] = a * 0.125f;
    }
    float mx = fmaxf(sj[0], sj[1]);
    for (int off = 32; off; off >>= 1) mx = fmaxf(mx, __shfl_down(mx, off, 64));
    if ((tid & 63) == 0) red[tid >> 6] = mx;
    __syncthreads();
    mx = fmaxf(fmaxf(red[0], red[1]), fmaxf(red[2], red[3]));
    float e0 = __expf(sj[0] - mx), e1 = __expf(sj[1] - mx);
    p[tid] = e0; p[tid + 256] = e1;
    float s = e0 + e1;
    for (int off = 32; off; off >>= 1) s += __shfl_down(s, off, 64);
    if ((tid & 63) == 0) red[4 + (tid >> 6)] = s;
    __syncthreads();
    float denom = red[4] + red[5] + red[6] + red[7];

    // P @ V : 4 chunks of 128 rows, 64 cols
    int o = tid & 63, cq = tid >> 6;
    float acc = 0.f;
    #pragma unroll 4
    for (int j = cq * 128; j < cq * 128 + 128; ++j)
        acc += p[j] * V[(size_t)j * 64 + o];
    pv[cq][o] = acc;
    __syncthreads();
    if (tid < 64)
        xde[tid] = (pv[0][tid] + pv[1][tid] + pv[2][tid] + pv[3][tid]) / denom;
    if (tid >= 64 && tid < 128) {
        int oo = tid - 64;
        float a = fgb[oo];
        #pragma unroll
        for (int j = 0; j < NBANDS * NC; ++j) {
            int band = j / NC, c = j % NC;
            a += pooled[((size_t)band * BATCH + b) * NC + c] * fgW[j * 64 + oo];
        }
        xout[oo] = eluf(a);
    }
    __syncthreads();
    if (tid < NC) {
        float a = fab[tid];
        for (int i = 0; i < 64; ++i) a += xout[i] * faW[i * NC + tid];
        for (int i = 0; i < 64; ++i) a += xde[i] * faW[(64 + i) * NC + tid];
        out[(size_t)b * NC + tid] = eluf(a);
    }
}

extern "C" void kernel_launch(void* const* d_in, const int* in_sizes, int n_in,
                              void* d_out, int out_size, void* d_ws, size_t ws_size,
                              hipStream_t stream) {
    const float* x     = (const float*)d_in[0];
    const int*   ei    = (const int*)  d_in[1];
    const float* de    = (const float*)d_in[3];
    const float* bn_g  = (const float*)d_in[4];
    const float* bn_b  = (const float*)d_in[5];
    const float* W     = (const float*)d_in[6];
    const float* attS  = (const float*)d_in[7];
    const float* attD  = (const float*)d_in[8];
    const float* gbias = (const float*)d_in[9];
    const float* fgW   = (const float*)d_in[10];
    const float* fgb   = (const float*)d_in[11];
    const float* ln_g  = (const float*)d_in[12];
    const float* ln_b  = (const float*)d_in[13];
    const float* qW    = (const float*)d_in[14];
    const float* qb    = (const float*)d_in[15];
    const float* kW    = (const float*)d_in[16];
    const float* kb    = (const float*)d_in[17];
    const float* vW    = (const float*)d_in[18];
    const float* vb    = (const float*)d_in[19];
    const float* faW   = (const float*)d_in[20];
    const float* fab   = (const float*)d_in[21];
    float* ws  = (float*)d_ws;
    float* out = (float*)d_out;

    hipMemsetAsync(d_ws, 0, 64 * sizeof(float), stream);
    bn_stats<<<dim3(NBANDS, 8), 256, 0, stream>>>(x, ws + WS_BN);
    gat_kernel<<<dim3(BATCH, NBANDS), 256, 0, stream>>>(
        x, ei, bn_g, bn_b, W, attS, attD, gbias, ws + WS_BN, ws + WS_POOLED);
    ln_qkv<<<BATCH, 256, 0, stream>>>(de, ln_g, ln_b, qW, qb, kW, kb, vW, vb,
                                      ws + WS_Q, ws + WS_K, ws + WS_V);
    attn_final<<<BATCH, 256, 0, stream>>>(ws + WS_Q, ws + WS_K, ws + WS_V,
                                          ws + WS_POOLED, fgW, fgb, faW, fab, out);
}

// Round 2
// 139.422 us; speedup vs baseline: 4.0112x; 4.0112x over previous
//
#include <hip/hip_runtime.h>
#include <math.h>

#define NBANDS 5
#define BATCH  512
#define NPG    62
#define NTOT   (BATCH*NPG)     // 31744
#define F_IN   5
#define NH     8
#define NC     3
#define HC     (NH*NC)         // 24
#define EG     (NPG*16)        // 992 edges per graph
#define ETOT   (BATCH*EG)      // 507904
#define EPG    (EG+NPG)        // 1054 incl self loops
#define DE_DIM 930

// workspace layout (floats)
#define WS_BN     0                    // 5 bands * 10 (sum[5], sumsq[5])
#define WS_POOLED 64                   // 5*512*3 = 7680
#define WS_Q      (WS_POOLED + NBANDS*BATCH*NC)
#define WS_K      (WS_Q + BATCH*64)
#define WS_V      (WS_K + BATCH*64)

__device__ __forceinline__ float eluf(float x) { return x > 0.f ? x : expm1f(x); }

// ---------------- kernel A: BN batch stats (partial sums, global atomics) ----
__global__ __launch_bounds__(256) void bn_stats(const float* __restrict__ x,
                                                float* __restrict__ ws) {
    int band = blockIdx.x;
    int chunk = blockIdx.y;                 // 8 chunks
    const int ROWS = NTOT / 8;              // 3968
    int r0 = chunk * ROWS;
    const float* xb = x + (size_t)band * NTOT * F_IN;
    float s[F_IN] = {0,0,0,0,0}, q[F_IN] = {0,0,0,0,0};
    for (int r = r0 + threadIdx.x; r < r0 + ROWS; r += 256) {
        const float* row = xb + (size_t)r * F_IN;
        #pragma unroll
        for (int f = 0; f < F_IN; ++f) { float v = row[f]; s[f] += v; q[f] += v * v; }
    }
    #pragma unroll
    for (int f = 0; f < F_IN; ++f) {
        for (int off = 32; off; off >>= 1) {
            s[f] += __shfl_down(s[f], off, 64);
            q[f] += __shfl_down(q[f], off, 64);
        }
    }
    if ((threadIdx.x & 63) == 0) {
        float* dst = ws + band * 10;
        #pragma unroll
        for (int f = 0; f < F_IN; ++f) {
            atomicAdd(&dst[f], s[f]);
            atomicAdd(&dst[5 + f], q[f]);
        }
    }
}

// ---------------- kernel B: per-(band,graph) GAT + mean pool ---------------
// CSR-by-destination gather formulation: zero contended atomics.
__global__ __launch_bounds__(256) void gat_kernel(
    const float* __restrict__ x, const int* __restrict__ ei,
    const float* __restrict__ bn_g, const float* __restrict__ bn_b,
    const float* __restrict__ Wg, const float* __restrict__ attSg,
    const float* __restrict__ attDg, const float* __restrict__ biasg,
    const float* __restrict__ ws_bn, float* __restrict__ pooled) {
    int g    = blockIdx.x;
    int band = blockIdx.y;
    __shared__ float Wl[F_IN * HC];          // 120
    __shared__ float attS[HC], attD[HC];
    __shared__ float xt[NPG * HC];           // 1488
    __shared__ float als[NPG * NH], ald[NPG * NH];  // 496 each
    __shared__ int   deg[NPG];
    __shared__ int   offs[NPG + 1];
    __shared__ int   cur[NPG];
    __shared__ int   csr[EPG];               // src ids grouped by dst
    __shared__ float outhc[NPG * HC];        // per (node,head,chan) result

    int tid = threadIdx.x;
    int nbase = g * NPG;

    if (tid < F_IN * HC) Wl[tid] = Wg[band * F_IN * HC + tid];
    if (tid >= 128 && tid < 128 + HC) attS[tid - 128] = attSg[band * HC + tid - 128];
    if (tid >= 160 && tid < 160 + HC) attD[tid - 160] = attDg[band * HC + tid - 160];
    if (tid < NPG) deg[tid] = 0;
    __syncthreads();

    const int* srcp = ei + (size_t)band * 2 * ETOT + (size_t)g * EG;
    const int* dstp = srcp + ETOT;

    // count in-degrees (62 counters, ~16-way avg contention, cheap)
    for (int e = tid; e < EG; e += 256) atomicAdd(&deg[dstp[e] - nbase], 1);

    // per-node: BN-normalize, xt = xn@W, attention logits
    if (tid < NPG) {
        const float* st = ws_bn + band * 10;
        const float* xr = x + (size_t)band * NTOT * F_IN + (size_t)(nbase + tid) * F_IN;
        float xn[F_IN];
        #pragma unroll
        for (int f = 0; f < F_IN; ++f) {
            float mu   = st[f] * (1.0f / NTOT);
            float var  = st[5 + f] * (1.0f / NTOT) - mu * mu;
            float rstd = rsqrtf(var + 1e-5f);
            xn[f] = (xr[f] - mu) * rstd * bn_g[band * F_IN + f] + bn_b[band * F_IN + f];
        }
        float xtv[HC];
        #pragma unroll
        for (int o = 0; o < HC; ++o) {
            float a = 0.f;
            #pragma unroll
            for (int f = 0; f < F_IN; ++f) a += xn[f] * Wl[f * HC + o];
            xtv[o] = a;
            xt[tid * HC + o] = a;
        }
        #pragma unroll
        for (int h = 0; h < NH; ++h) {
            float as = 0.f, ad = 0.f;
            #pragma unroll
            for (int c = 0; c < NC; ++c) {
                as += xtv[h * NC + c] * attS[h * NC + c];
                ad += xtv[h * NC + c] * attD[h * NC + c];
            }
            als[tid * NH + h] = as;
            ald[tid * NH + h] = ad;
        }
    }
    __syncthreads();

    // exclusive scan (serial over 62 — trivial); +1 per node for self loop
    if (tid == 0) {
        int r = 0;
        for (int d = 0; d < NPG; ++d) { offs[d] = r; r += deg[d] + 1; }
        offs[NPG] = r;   // == EPG
    }
    __syncthreads();
    // self-loop gets the deterministic first slot; edges scatter after
    if (tid < NPG) { csr[offs[tid]] = tid; cur[tid] = offs[tid] + 1; }
    __syncthreads();
    for (int e = tid; e < EG; e += 256) {
        int ld = dstp[e] - nbase;
        int p = atomicAdd(&cur[ld], 1);
        csr[p] = srcp[e] - nbase;
    }
    __syncthreads();

    // gather phase: one (dst,head) pair per work item, registers only
    for (int p = tid; p < NPG * NH; p += 256) {
        int d = p >> 3, h = p & 7;
        int s0 = offs[d], s1 = offs[d + 1];
        float adv = ald[d * NH + h];
        float mx = -1e30f;
        for (int e = s0; e < s1; ++e) {
            float v = als[csr[e] * NH + h] + adv;
            v = v > 0.f ? v : 0.2f * v;
            mx = fmaxf(mx, v);
        }
        float den = 0.f, m0 = 0.f, m1 = 0.f, m2 = 0.f;
        for (int e = s0; e < s1; ++e) {
            int s = csr[e];
            float v = als[s * NH + h] + adv;
            v = v > 0.f ? v : 0.2f * v;
            float ex = __expf(v - mx);
            den += ex;
            m0 += ex * xt[s * HC + h * NC + 0];
            m1 += ex * xt[s * HC + h * NC + 1];
            m2 += ex * xt[s * HC + h * NC + 2];
        }
        float rd = 1.0f / den;
        outhc[d * HC + h * NC + 0] = m0 * rd;
        outhc[d * HC + h * NC + 1] = m1 * rd;
        outhc[d * HC + h * NC + 2] = m2 * rd;
    }
    __syncthreads();

    // node output (head mean + bias + elu) then graph mean pool
    float oc[NC] = {0.f, 0.f, 0.f};
    if (tid < NPG) {
        #pragma unroll
        for (int c = 0; c < NC; ++c) {
            float a = 0.f;
            #pragma unroll
            for (int h = 0; h < NH; ++h) a += outhc[tid * HC + h * NC + c];
            a = a * (1.0f / NH) + biasg[band * NC + c];
            oc[c] = eluf(a);
        }
    }
    if (tid < 64) {   // wave 0 holds all 62 node threads
        #pragma unroll
        for (int c = 0; c < NC; ++c) {
            float v = oc[c];
            for (int off = 32; off; off >>= 1) v += __shfl_down(v, off, 64);
            if (tid == 0)
                pooled[((size_t)band * BATCH + g) * NC + c] = v * (1.0f / NPG);
        }
    }
}

// ---------------- kernel C1: LayerNorm + Q/K/V projections -----------------
__global__ __launch_bounds__(256) void ln_qkv(
    const float* __restrict__ de, const float* __restrict__ ln_g,
    const float* __restrict__ ln_b,
    const float* __restrict__ qW, const float* __restrict__ qb,
    const float* __restrict__ kW, const float* __restrict__ kb,
    const float* __restrict__ vW, const float* __restrict__ vb,
    float* __restrict__ Q, float* __restrict__ K, float* __restrict__ V) {
    int b = blockIdx.x;
    __shared__ float dn[DE_DIM];
    __shared__ float red[8];
    int tid = threadIdx.x;
    const float* row = de + (size_t)b * DE_DIM;
    float s1 = 0.f, s2 = 0.f;
    for (int i = tid; i < DE_DIM; i += 256) {
        float v = row[i]; dn[i] = v; s1 += v; s2 += v * v;
    }
    for (int off = 32; off; off >>= 1) {
        s1 += __shfl_down(s1, off, 64);
        s2 += __shfl_down(s2, off, 64);
    }
    if ((tid & 63) == 0) { red[tid >> 6] = s1; red[4 + (tid >> 6)] = s2; }
    __syncthreads();
    float mu   = (red[0] + red[1] + red[2] + red[3]) * (1.0f / DE_DIM);
    float var  = (red[4] + red[5] + red[6] + red[7]) * (1.0f / DE_DIM) - mu * mu;
    float rstd = rsqrtf(var + 1e-5f);
    for (int i = tid; i < DE_DIM; i += 256)
        dn[i] = (dn[i] - mu) * rstd * ln_g[i] + ln_b[i];
    __syncthreads();

    if (tid < 192) {
        int m = tid >> 6, col = tid & 63;
        const float* Wm = (m == 0) ? qW : (m == 1) ? kW : vW;
        const float* bm = (m == 0) ? qb : (m == 1) ? kb : vb;
        float acc = 0.f;
        #pragma unroll 5
        for (int i = 0; i < DE_DIM; ++i) acc += dn[i] * Wm[(size_t)i * 64 + col];
        acc += bm[col];
        float* o = (m == 0) ? Q : (m == 1) ? K : V;
        o[(size_t)b * 64 + col] = acc;
    }
}

// ---------------- kernel C2: attention + fusion tail -----------------------
__global__ __launch_bounds__(256) void attn_final(
    const float* __restrict__ Q, const float* __restrict__ K,
    const float* __restrict__ V, const float* __restrict__ pooled,
    const float* __restrict__ fgW, const float* __restrict__ fgb,
    const float* __restrict__ faW, const float* __restrict__ fab,
    float* __restrict__ out) {
    int b = blockIdx.x;
    int tid = threadIdx.x;
    __shared__ float qrow[64];
    __shared__ float p[BATCH];
    __shared__ float red[8];
    __shared__ float pv[4][64];
    __shared__ float xde[64], xout[64];
    if (tid < 64) qrow[tid] = Q[(size_t)b * 64 + tid];
    __syncthreads();

    float sj[2];
    #pragma unroll
    for (int r = 0; r < 2; ++r) {
        int j = tid + r * 256;
        const float4* k4 = (const float4*)(K + (size_t)j * 64);
        float a = 0.f;
        #pragma unroll
        for (int i = 0; i < 16; ++i) {
            float4 kv = k4[i];
            a += qrow[4*i]   * kv.x + qrow[4*i+1] * kv.y
               + qrow[4*i+2] * kv.z + qrow[4*i+3] * kv.w;
        }
        sj[r] = a * 0.125f;
    }
    float mx = fmaxf(sj[0], sj[1]);
    for (int off = 32; off; off >>= 1) mx = fmaxf(mx, __shfl_down(mx, off, 64));
    if ((tid & 63) == 0) red[tid >> 6] = mx;
    __syncthreads();
    mx = fmaxf(fmaxf(red[0], red[1]), fmaxf(red[2], red[3]));
    float e0 = __expf(sj[0] - mx), e1 = __expf(sj[1] - mx);
    p[tid] = e0; p[tid + 256] = e1;
    float s = e0 + e1;
    for (int off = 32; off; off >>= 1) s += __shfl_down(s, off, 64);
    if ((tid & 63) == 0) red[4 + (tid >> 6)] = s;
    __syncthreads();
    float denom = red[4] + red[5] + red[6] + red[7];

    // P @ V : 4 chunks of 128 rows, 64 cols
    int o = tid & 63, cq = tid >> 6;
    float acc = 0.f;
    #pragma unroll 4
    for (int j = cq * 128; j < cq * 128 + 128; ++j)
        acc += p[j] * V[(size_t)j * 64 + o];
    pv[cq][o] = acc;
    __syncthreads();
    if (tid < 64)
        xde[tid] = (pv[0][tid] + pv[1][tid] + pv[2][tid] + pv[3][tid]) / denom;
    if (tid >= 64 && tid < 128) {
        int oo = tid - 64;
        float a = fgb[oo];
        #pragma unroll
        for (int j = 0; j < NBANDS * NC; ++j) {
            int band = j / NC, c = j % NC;
            a += pooled[((size_t)band * BATCH + b) * NC + c] * fgW[j * 64 + oo];
        }
        xout[oo] = eluf(a);
    }
    __syncthreads();
    if (tid < NC) {
        float a = fab[tid];
        for (int i = 0; i < 64; ++i) a += xout[i] * faW[i * NC + tid];
        for (int i = 0; i < 64; ++i) a += xde[i] * faW[(64 + i) * NC + tid];
        out[(size_t)b * NC + tid] = eluf(a);
    }
}

extern "C" void kernel_launch(void* const* d_in, const int* in_sizes, int n_in,
                              void* d_out, int out_size, void* d_ws, size_t ws_size,
                              hipStream_t stream) {
    const float* x     = (const float*)d_in[0];
    const int*   ei    = (const int*)  d_in[1];
    const float* de    = (const float*)d_in[3];
    const float* bn_g  = (const float*)d_in[4];
    const float* bn_b  = (const float*)d_in[5];
    const float* W     = (const float*)d_in[6];
    const float* attS  = (const float*)d_in[7];
    const float* attD  = (const float*)d_in[8];
    const float* gbias = (const float*)d_in[9];
    const float* fgW   = (const float*)d_in[10];
    const float* fgb   = (const float*)d_in[11];
    const float* ln_g  = (const float*)d_in[12];
    const float* ln_b  = (const float*)d_in[13];
    const float* qW    = (const float*)d_in[14];
    const float* qb    = (const float*)d_in[15];
    const float* kW    = (const float*)d_in[16];
    const float* kb    = (const float*)d_in[17];
    const float* vW    = (const float*)d_in[18];
    const float* vb    = (const float*)d_in[19];
    const float* faW   = (const float*)d_in[20];
    const float* fab   = (const float*)d_in[21];
    float* ws  = (float*)d_ws;
    float* out = (float*)d_out;

    hipMemsetAsync(d_ws, 0, 64 * sizeof(float), stream);
    bn_stats<<<dim3(NBANDS, 8), 256, 0, stream>>>(x, ws + WS_BN);
    gat_kernel<<<dim3(BATCH, NBANDS), 256, 0, stream>>>(
        x, ei, bn_g, bn_b, W, attS, attD, gbias, ws + WS_BN, ws + WS_POOLED);
    ln_qkv<<<BATCH, 256, 0, stream>>>(de, ln_g, ln_b, qW, qb, kW, kb, vW, vb,
                                      ws + WS_Q, ws + WS_K, ws + WS_V);
    attn_final<<<BATCH, 256, 0, stream>>>(ws + WS_Q, ws + WS_K, ws + WS_V,
                                          ws + WS_POOLED, fgW, fgb, faW, fab, out);
}

// Round 3
// 120.782 us; speedup vs baseline: 4.6302x; 1.1543x over previous
//
#include <hip/hip_runtime.h>
#include <math.h>

#define NBANDS 5
#define BATCH  512
#define NPG    62
#define NTOT   (BATCH*NPG)     // 31744
#define F_IN   5
#define NH     8
#define NC     3
#define HC     (NH*NC)         // 24
#define EG     (NPG*16)        // 992 edges per graph
#define ETOT   (BATCH*EG)      // 507904
#define EPG    (EG+NPG)        // 1054 incl self loops
#define DE_DIM 930

// workspace layout (floats)
#define WS_BN     0                    // 5 bands * 10 (sum[5], sumsq[5])
#define WS_POOLED 64                   // 5*512*3 = 7680
#define WS_Q      (WS_POOLED + NBANDS*BATCH*NC)
#define WS_K      (WS_Q + BATCH*64)
#define WS_V      (WS_K + BATCH*64)

__device__ __forceinline__ float eluf(float x) { return x > 0.f ? x : expm1f(x); }

// ---------------- kernel A: BN batch stats (partial sums, global atomics) ----
__global__ __launch_bounds__(256) void bn_stats(const float* __restrict__ x,
                                                float* __restrict__ ws) {
    int band = blockIdx.x;
    int chunk = blockIdx.y;                 // 8 chunks
    const int ROWS = NTOT / 8;              // 3968
    int r0 = chunk * ROWS;
    const float* xb = x + (size_t)band * NTOT * F_IN;
    float s[F_IN] = {0,0,0,0,0}, q[F_IN] = {0,0,0,0,0};
    for (int r = r0 + threadIdx.x; r < r0 + ROWS; r += 256) {
        const float* row = xb + (size_t)r * F_IN;
        #pragma unroll
        for (int f = 0; f < F_IN; ++f) { float v = row[f]; s[f] += v; q[f] += v * v; }
    }
    #pragma unroll
    for (int f = 0; f < F_IN; ++f) {
        for (int off = 32; off; off >>= 1) {
            s[f] += __shfl_down(s[f], off, 64);
            q[f] += __shfl_down(q[f], off, 64);
        }
    }
    if ((threadIdx.x & 63) == 0) {
        float* dst = ws + band * 10;
        #pragma unroll
        for (int f = 0; f < F_IN; ++f) {
            atomicAdd(&dst[f], s[f]);
            atomicAdd(&dst[5 + f], q[f]);
        }
    }
}

// ---------------- kernel B: per-(band,graph) GAT + mean pool ---------------
// CSR-by-destination gather formulation: zero contended atomics.
__global__ __launch_bounds__(256) void gat_kernel(
    const float* __restrict__ x, const int* __restrict__ ei,
    const float* __restrict__ bn_g, const float* __restrict__ bn_b,
    const float* __restrict__ Wg, const float* __restrict__ attSg,
    const float* __restrict__ attDg, const float* __restrict__ biasg,
    const float* __restrict__ ws_bn, float* __restrict__ pooled) {
    int g    = blockIdx.x;
    int band = blockIdx.y;
    __shared__ float Wl[F_IN * HC];          // 120
    __shared__ float attS[HC], attD[HC];
    __shared__ float xt[NPG * HC];           // 1488
    __shared__ float als[NPG * NH], ald[NPG * NH];  // 496 each
    __shared__ int   deg[NPG];
    __shared__ int   offs[NPG + 1];
    __shared__ int   cur[NPG];
    __shared__ int   csr[EPG];               // src ids grouped by dst
    __shared__ float outhc[NPG * HC];        // per (node,head,chan) result

    int tid = threadIdx.x;
    int nbase = g * NPG;

    if (tid < F_IN * HC) Wl[tid] = Wg[band * F_IN * HC + tid];
    if (tid >= 128 && tid < 128 + HC) attS[tid - 128] = attSg[band * HC + tid - 128];
    if (tid >= 160 && tid < 160 + HC) attD[tid - 160] = attDg[band * HC + tid - 160];
    if (tid < NPG) deg[tid] = 0;
    __syncthreads();

    const int* srcp = ei + (size_t)band * 2 * ETOT + (size_t)g * EG;
    const int* dstp = srcp + ETOT;

    // count in-degrees (62 counters, ~16-way avg contention, cheap)
    for (int e = tid; e < EG; e += 256) atomicAdd(&deg[dstp[e] - nbase], 1);

    // per-node: BN-normalize, xt = xn@W, attention logits
    if (tid < NPG) {
        const float* st = ws_bn + band * 10;
        const float* xr = x + (size_t)band * NTOT * F_IN + (size_t)(nbase + tid) * F_IN;
        float xn[F_IN];
        #pragma unroll
        for (int f = 0; f < F_IN; ++f) {
            float mu   = st[f] * (1.0f / NTOT);
            float var  = st[5 + f] * (1.0f / NTOT) - mu * mu;
            float rstd = rsqrtf(var + 1e-5f);
            xn[f] = (xr[f] - mu) * rstd * bn_g[band * F_IN + f] + bn_b[band * F_IN + f];
        }
        float xtv[HC];
        #pragma unroll
        for (int o = 0; o < HC; ++o) {
            float a = 0.f;
            #pragma unroll
            for (int f = 0; f < F_IN; ++f) a += xn[f] * Wl[f * HC + o];
            xtv[o] = a;
            xt[tid * HC + o] = a;
        }
        #pragma unroll
        for (int h = 0; h < NH; ++h) {
            float as = 0.f, ad = 0.f;
            #pragma unroll
            for (int c = 0; c < NC; ++c) {
                as += xtv[h * NC + c] * attS[h * NC + c];
                ad += xtv[h * NC + c] * attD[h * NC + c];
            }
            als[tid * NH + h] = as;
            ald[tid * NH + h] = ad;
        }
    }
    __syncthreads();

    // exclusive scan (serial over 62 — trivial); +1 per node for self loop
    if (tid == 0) {
        int r = 0;
        for (int d = 0; d < NPG; ++d) { offs[d] = r; r += deg[d] + 1; }
        offs[NPG] = r;   // == EPG
    }
    __syncthreads();
    // self-loop gets the deterministic first slot; edges scatter after
    if (tid < NPG) { csr[offs[tid]] = tid; cur[tid] = offs[tid] + 1; }
    __syncthreads();
    for (int e = tid; e < EG; e += 256) {
        int ld = dstp[e] - nbase;
        int p = atomicAdd(&cur[ld], 1);
        csr[p] = srcp[e] - nbase;
    }
    __syncthreads();

    // gather phase: one (dst,head) pair per work item, registers only
    for (int p = tid; p < NPG * NH; p += 256) {
        int d = p >> 3, h = p & 7;
        int s0 = offs[d], s1 = offs[d + 1];
        float adv = ald[d * NH + h];
        float mx = -1e30f;
        for (int e = s0; e < s1; ++e) {
            float v = als[csr[e] * NH + h] + adv;
            v = v > 0.f ? v : 0.2f * v;
            mx = fmaxf(mx, v);
        }
        float den = 0.f, m0 = 0.f, m1 = 0.f, m2 = 0.f;
        for (int e = s0; e < s1; ++e) {
            int s = csr[e];
            float v = als[s * NH + h] + adv;
            v = v > 0.f ? v : 0.2f * v;
            float ex = __expf(v - mx);
            den += ex;
            m0 += ex * xt[s * HC + h * NC + 0];
            m1 += ex * xt[s * HC + h * NC + 1];
            m2 += ex * xt[s * HC + h * NC + 2];
        }
        float rd = 1.0f / den;
        outhc[d * HC + h * NC + 0] = m0 * rd;
        outhc[d * HC + h * NC + 1] = m1 * rd;
        outhc[d * HC + h * NC + 2] = m2 * rd;
    }
    __syncthreads();

    // node output (head mean + bias + elu) then graph mean pool
    float oc[NC] = {0.f, 0.f, 0.f};
    if (tid < NPG) {
        #pragma unroll
        for (int c = 0; c < NC; ++c) {
            float a = 0.f;
            #pragma unroll
            for (int h = 0; h < NH; ++h) a += outhc[tid * HC + h * NC + c];
            a = a * (1.0f / NH) + biasg[band * NC + c];
            oc[c] = eluf(a);
        }
    }
    if (tid < 64) {   // wave 0 holds all 62 node threads
        #pragma unroll
        for (int c = 0; c < NC; ++c) {
            float v = oc[c];
            for (int off = 32; off; off >>= 1) v += __shfl_down(v, off, 64);
            if (tid == 0)
                pooled[((size_t)band * BATCH + g) * NC + c] = v * (1.0f / NPG);
        }
    }
}

// ------------- kernel C1: fused LayerNorm + one of Q/K/V projections -------
// grid = (BATCH/4 row-tiles, 3 matrices); block = 256.
// Phase 1: wave w LayerNorms row r0+w into LDS.
// Phase 2: thread (rw=tid>>6, col=tid&63) computes out[r0+rw][col] with a
//          930-long dot, 10 independent accumulator chains for ILP.
__global__ __launch_bounds__(256) void qkv_fused(
    const float* __restrict__ de, const float* __restrict__ ln_g,
    const float* __restrict__ ln_b,
    const float* __restrict__ qW, const float* __restrict__ qb,
    const float* __restrict__ kW, const float* __restrict__ kb,
    const float* __restrict__ vW, const float* __restrict__ vb,
    float* __restrict__ Q, float* __restrict__ K, float* __restrict__ V) {
    int r0 = blockIdx.x * 4;
    int m  = blockIdx.y;
    __shared__ float dn[4][DE_DIM];

    int tid  = threadIdx.x;
    int w    = tid >> 6;          // wave id == local row
    int lane = tid & 63;

    // phase 1: load + stats
    const float* row = de + (size_t)(r0 + w) * DE_DIM;
    float s1 = 0.f, s2 = 0.f;
    for (int i = lane; i < DE_DIM; i += 64) {
        float v = row[i];
        dn[w][i] = v;
        s1 += v; s2 += v * v;
    }
    #pragma unroll
    for (int off = 32; off; off >>= 1) {
        s1 += __shfl_down(s1, off, 64);
        s2 += __shfl_down(s2, off, 64);
    }
    float mu   = __shfl(s1, 0, 64) * (1.0f / DE_DIM);
    float var  = __shfl(s2, 0, 64) * (1.0f / DE_DIM) - mu * mu;
    float rstd = rsqrtf(var + 1e-5f);
    for (int i = lane; i < DE_DIM; i += 64)
        dn[w][i] = (dn[w][i] - mu) * rstd * ln_g[i] + ln_b[i];
    __syncthreads();

    // phase 2: 4 rows x 64 cols, one output per thread
    const float* Wm = (m == 0) ? qW : (m == 1) ? kW : vW;
    const float* bm = (m == 0) ? qb : (m == 1) ? kb : vb;
    float*       Om = (m == 0) ? Q  : (m == 1) ? K  : V;
    int rw = w, col = lane;
    float a[10];
    #pragma unroll
    for (int j = 0; j < 10; ++j) a[j] = 0.f;
    for (int i = 0; i < DE_DIM; i += 10) {   // 930 = 93 * 10
        #pragma unroll
        for (int j = 0; j < 10; ++j)
            a[j] += dn[rw][i + j] * Wm[(size_t)(i + j) * 64 + col];
    }
    float acc = (((a[0] + a[1]) + (a[2] + a[3])) + ((a[4] + a[5]) + (a[6] + a[7])))
              + (a[8] + a[9]) + bm[col];
    Om[(size_t)(r0 + rw) * 64 + col] = acc;
}

// ---------------- kernel C2: attention + fusion tail -----------------------
__global__ __launch_bounds__(256) void attn_final(
    const float* __restrict__ Q, const float* __restrict__ K,
    const float* __restrict__ V, const float* __restrict__ pooled,
    const float* __restrict__ fgW, const float* __restrict__ fgb,
    const float* __restrict__ faW, const float* __restrict__ fab,
    float* __restrict__ out) {
    int b = blockIdx.x;
    int tid = threadIdx.x;
    __shared__ float qrow[64];
    __shared__ float p[BATCH];
    __shared__ float red[8];
    __shared__ float pv[4][64];
    __shared__ float xde[64], xout[64];
    if (tid < 64) qrow[tid] = Q[(size_t)b * 64 + tid];
    __syncthreads();

    float sj[2];
    #pragma unroll
    for (int r = 0; r < 2; ++r) {
        int j = tid + r * 256;
        const float4* k4 = (const float4*)(K + (size_t)j * 64);
        float a = 0.f;
        #pragma unroll
        for (int i = 0; i < 16; ++i) {
            float4 kv = k4[i];
            a += qrow[4*i]   * kv.x + qrow[4*i+1] * kv.y
               + qrow[4*i+2] * kv.z + qrow[4*i+3] * kv.w;
        }
        sj[r] = a * 0.125f;
    }
    float mx = fmaxf(sj[0], sj[1]);
    for (int off = 32; off; off >>= 1) mx = fmaxf(mx, __shfl_down(mx, off, 64));
    if ((tid & 63) == 0) red[tid >> 6] = mx;
    __syncthreads();
    mx = fmaxf(fmaxf(red[0], red[1]), fmaxf(red[2], red[3]));
    float e0 = __expf(sj[0] - mx), e1 = __expf(sj[1] - mx);
    p[tid] = e0; p[tid + 256] = e1;
    float s = e0 + e1;
    for (int off = 32; off; off >>= 1) s += __shfl_down(s, off, 64);
    if ((tid & 63) == 0) red[4 + (tid >> 6)] = s;
    __syncthreads();
    float denom = red[4] + red[5] + red[6] + red[7];

    // P @ V : 4 chunks of 128 rows, 64 cols
    int o = tid & 63, cq = tid >> 6;
    float acc = 0.f;
    #pragma unroll 4
    for (int j = cq * 128; j < cq * 128 + 128; ++j)
        acc += p[j] * V[(size_t)j * 64 + o];
    pv[cq][o] = acc;
    __syncthreads();
    if (tid < 64)
        xde[tid] = (pv[0][tid] + pv[1][tid] + pv[2][tid] + pv[3][tid]) / denom;
    if (tid >= 64 && tid < 128) {
        int oo = tid - 64;
        float a = fgb[oo];
        #pragma unroll
        for (int j = 0; j < NBANDS * NC; ++j) {
            int band = j / NC, c = j % NC;
            a += pooled[((size_t)band * BATCH + b) * NC + c] * fgW[j * 64 + oo];
        }
        xout[oo] = eluf(a);
    }
    __syncthreads();
    if (tid < NC) {
        float a = fab[tid];
        for (int i = 0; i < 64; ++i) a += xout[i] * faW[i * NC + tid];
        for (int i = 0; i < 64; ++i) a += xde[i] * faW[(64 + i) * NC + tid];
        out[(size_t)b * NC + tid] = eluf(a);
    }
}

extern "C" void kernel_launch(void* const* d_in, const int* in_sizes, int n_in,
                              void* d_out, int out_size, void* d_ws, size_t ws_size,
                              hipStream_t stream) {
    const float* x     = (const float*)d_in[0];
    const int*   ei    = (const int*)  d_in[1];
    const float* de    = (const float*)d_in[3];
    const float* bn_g  = (const float*)d_in[4];
    const float* bn_b  = (const float*)d_in[5];
    const float* W     = (const float*)d_in[6];
    const float* attS  = (const float*)d_in[7];
    const float* attD  = (const float*)d_in[8];
    const float* gbias = (const float*)d_in[9];
    const float* fgW   = (const float*)d_in[10];
    const float* fgb   = (const float*)d_in[11];
    const float* ln_g  = (const float*)d_in[12];
    const float* ln_b  = (const float*)d_in[13];
    const float* qW    = (const float*)d_in[14];
    const float* qb    = (const float*)d_in[15];
    const float* kW    = (const float*)d_in[16];
    const float* kb    = (const float*)d_in[17];
    const float* vW    = (const float*)d_in[18];
    const float* vb    = (const float*)d_in[19];
    const float* faW   = (const float*)d_in[20];
    const float* fab   = (const float*)d_in[21];
    float* ws  = (float*)d_ws;
    float* out = (float*)d_out;

    hipMemsetAsync(d_ws, 0, 64 * sizeof(float), stream);
    bn_stats<<<dim3(NBANDS, 8), 256, 0, stream>>>(x, ws + WS_BN);
    gat_kernel<<<dim3(BATCH, NBANDS), 256, 0, stream>>>(
        x, ei, bn_g, bn_b, W, attS, attD, gbias, ws + WS_BN, ws + WS_POOLED);
    qkv_fused<<<dim3(BATCH / 4, 3), 256, 0, stream>>>(
        de, ln_g, ln_b, qW, qb, kW, kb, vW, vb,
        ws + WS_Q, ws + WS_K, ws + WS_V);
    attn_final<<<BATCH, 256, 0, stream>>>(ws + WS_Q, ws + WS_K, ws + WS_V,
                                          ws + WS_POOLED, fgW, fgb, faW, fab, out);
}

// Round 4
// 103.542 us; speedup vs baseline: 5.4011x; 1.1665x over previous
//
#include <hip/hip_runtime.h>
#include <math.h>

#define NBANDS 5
#define BATCH  512
#define NPG    62
#define NTOT   (BATCH*NPG)     // 31744
#define F_IN   5
#define NH     8
#define NC     3
#define HC     (NH*NC)         // 24
#define EG     (NPG*16)        // 992 edges per graph
#define ETOT   (BATCH*EG)      // 507904
#define EPG    (EG+NPG)        // 1054 incl self loops
#define DE_DIM 930
#define KS     5
#define KLEN   186             // 930/5, = 31*6

// workspace layout (floats)
#define WS_BN     0                            // 5*10 + pad
#define WS_POOLED 64                           // 5*512*3 = 7680
#define WS_Q      (WS_POOLED + NBANDS*BATCH*NC)
#define WS_K      (WS_Q + BATCH*64)
#define WS_V      (WS_K + BATCH*64)
#define WS_DN     (WS_V + BATCH*64)            // 512*930 = 476160
#define WS_PART   (WS_DN + BATCH*DE_DIM)       // 3*5*512*64 = 491520
#define WS_END    (WS_PART + 3*KS*BATCH*64)

__device__ __forceinline__ float eluf(float x) { return x > 0.f ? x : expm1f(x); }

// ---------------- kernel A: BN batch stats (partial sums, global atomics) ----
__global__ __launch_bounds__(256) void bn_stats(const float* __restrict__ x,
                                                float* __restrict__ ws) {
    int band = blockIdx.x;
    int chunk = blockIdx.y;                 // 8 chunks
    const int ROWS = NTOT / 8;              // 3968
    int r0 = chunk * ROWS;
    const float* xb = x + (size_t)band * NTOT * F_IN;
    float s[F_IN] = {0,0,0,0,0}, q[F_IN] = {0,0,0,0,0};
    for (int r = r0 + threadIdx.x; r < r0 + ROWS; r += 256) {
        const float* row = xb + (size_t)r * F_IN;
        #pragma unroll
        for (int f = 0; f < F_IN; ++f) { float v = row[f]; s[f] += v; q[f] += v * v; }
    }
    #pragma unroll
    for (int f = 0; f < F_IN; ++f) {
        for (int off = 32; off; off >>= 1) {
            s[f] += __shfl_down(s[f], off, 64);
            q[f] += __shfl_down(q[f], off, 64);
        }
    }
    if ((threadIdx.x & 63) == 0) {
        float* dst = ws + band * 10;
        #pragma unroll
        for (int f = 0; f < F_IN; ++f) {
            atomicAdd(&dst[f], s[f]);
            atomicAdd(&dst[5 + f], q[f]);
        }
    }
}

// ---------------- kernel B: per-(band,graph) GAT + mean pool ---------------
// CSR gather, single-pass softmax (no max subtraction: logits are O(1) in
// fp32, exp cannot overflow), wave-parallel scan, shfl head-mean.
__global__ __launch_bounds__(256) void gat_kernel(
    const float* __restrict__ x, const int* __restrict__ ei,
    const float* __restrict__ bn_g, const float* __restrict__ bn_b,
    const float* __restrict__ Wg, const float* __restrict__ attSg,
    const float* __restrict__ attDg, const float* __restrict__ biasg,
    const float* __restrict__ ws_bn, float* __restrict__ pooled) {
    int g    = blockIdx.x;
    int band = blockIdx.y;
    __shared__ float Wl[F_IN * HC];                 // 120
    __shared__ float attS[HC], attD[HC];
    __shared__ float xns[NPG * F_IN];               // 310
    __shared__ float xt[NPG * HC];                  // 1488
    __shared__ float als[NPG * NH], ald[NPG * NH];  // 496 each
    __shared__ int   deg[NPG];
    __shared__ int   offs[NPG + 1];
    __shared__ int   cur[NPG];
    __shared__ int   csr[EPG];                      // src ids grouped by dst
    __shared__ float outd[NPG][NC];                 // per-node head-mean result

    int tid = threadIdx.x;
    int lane = tid & 63;
    int nbase = g * NPG;

    if (tid < F_IN * HC) Wl[tid] = Wg[band * F_IN * HC + tid];
    if (tid >= 128 && tid < 128 + HC) attS[tid - 128] = attSg[band * HC + tid - 128];
    if (tid >= 160 && tid < 160 + HC) attD[tid - 160] = attDg[band * HC + tid - 160];
    if (tid < NPG) deg[tid] = 0;
    __syncthreads();

    const int* srcp = ei + (size_t)band * 2 * ETOT + (size_t)g * EG;
    const int* dstp = srcp + ETOT;

    // phase 2: in-degree count (all threads) + BN-normalized features (tid<62)
    for (int e = tid; e < EG; e += 256) atomicAdd(&deg[dstp[e] - nbase], 1);
    if (tid < NPG) {
        const float* st = ws_bn + band * 10;
        const float* xr = x + (size_t)band * NTOT * F_IN + (size_t)(nbase + tid) * F_IN;
        #pragma unroll
        for (int f = 0; f < F_IN; ++f) {
            float mu   = st[f] * (1.0f / NTOT);
            float var  = st[5 + f] * (1.0f / NTOT) - mu * mu;
            float rstd = rsqrtf(var + 1e-5f);
            xns[tid * F_IN + f] =
                (xr[f] - mu) * rstd * bn_g[band * F_IN + f] + bn_b[band * F_IN + f];
        }
    }
    __syncthreads();

    // phase 3: wave0 does the exclusive scan; everyone computes xt
    if (tid < 64) {
        int dv = (tid < NPG) ? deg[tid] + 1 : 0;   // +1 self loop
        int sc = dv;
        #pragma unroll
        for (int off = 1; off < 64; off <<= 1) {
            int t = __shfl_up(sc, off, 64);
            if (lane >= off) sc += t;
        }
        if (tid < NPG) offs[tid + 1] = sc;
        if (tid == 0)  offs[0] = 0;
    }
    for (int p = tid; p < NPG * HC; p += 256) {
        int n = p / HC, o = p % HC;
        float a = 0.f;
        #pragma unroll
        for (int f = 0; f < F_IN; ++f) a += xns[n * F_IN + f] * Wl[f * HC + o];
        xt[p] = a;
    }
    __syncthreads();

    // phase 4: self-loop slot + cur init; attention logits
    if (tid < NPG) { csr[offs[tid]] = tid; cur[tid] = offs[tid] + 1; }
    for (int p = tid; p < NPG * NH; p += 256) {
        int n = p >> 3, h = p & 7;
        float as = 0.f, ad = 0.f;
        #pragma unroll
        for (int c = 0; c < NC; ++c) {
            float v = xt[n * HC + h * NC + c];
            as += v * attS[h * NC + c];
            ad += v * attD[h * NC + c];
        }
        als[p] = as;
        ald[p] = ad;
    }
    __syncthreads();

    // phase 5: CSR scatter
    for (int e = tid; e < EG; e += 256) {
        int ld = dstp[e] - nbase;
        int p = atomicAdd(&cur[ld], 1);
        csr[p] = srcp[e] - nbase;
    }
    __syncthreads();

    // phase 6: gather — one (dst,head) per thread, single pass, registers only
    for (int p = tid; p < NPG * NH; p += 256) {
        int d = p >> 3, h = p & 7;
        int s0 = offs[d], s1 = offs[d + 1];
        float adv = ald[p];
        float den = 0.f, m0 = 0.f, m1 = 0.f, m2 = 0.f;
        for (int e = s0; e < s1; ++e) {
            int s = csr[e];
            float v = als[s * NH + h] + adv;
            v = v > 0.f ? v : 0.2f * v;
            float ex = __expf(v);
            den += ex;
            m0 += ex * xt[s * HC + h * NC + 0];
            m1 += ex * xt[s * HC + h * NC + 1];
            m2 += ex * xt[s * HC + h * NC + 2];
        }
        float rd = 1.0f / den;
        float o0 = m0 * rd, o1 = m1 * rd, o2 = m2 * rd;
        // head mean across the 8-lane group (496 = 62*8, groups never split)
        #pragma unroll
        for (int off = 1; off < 8; off <<= 1) {
            o0 += __shfl_xor(o0, off, 64);
            o1 += __shfl_xor(o1, off, 64);
            o2 += __shfl_xor(o2, off, 64);
        }
        if (h == 0) { outd[d][0] = o0; outd[d][1] = o1; outd[d][2] = o2; }
    }
    __syncthreads();

    // node output (head mean + bias + elu) then graph mean pool
    float oc[NC] = {0.f, 0.f, 0.f};
    if (tid < NPG) {
        #pragma unroll
        for (int c = 0; c < NC; ++c)
            oc[c] = eluf(outd[tid][c] * (1.0f / NH) + biasg[band * NC + c]);
    }
    if (tid < 64) {
        #pragma unroll
        for (int c = 0; c < NC; ++c) {
            float v = oc[c];
            for (int off = 32; off; off >>= 1) v += __shfl_down(v, off, 64);
            if (tid == 0)
                pooled[((size_t)band * BATCH + g) * NC + c] = v * (1.0f / NPG);
        }
    }
}

// ---------------- kernel C0: LayerNorm de -> dn (workspace) ----------------
__global__ __launch_bounds__(256) void ln_kernel(
    const float* __restrict__ de, const float* __restrict__ ln_g,
    const float* __restrict__ ln_b, float* __restrict__ dn) {
    int r    = blockIdx.x * 4 + (threadIdx.x >> 6);
    int lane = threadIdx.x & 63;
    const float* row = de + (size_t)r * DE_DIM;
    float s1 = 0.f, s2 = 0.f;
    for (int i = lane; i < DE_DIM; i += 64) {
        float v = row[i]; s1 += v; s2 += v * v;
    }
    #pragma unroll
    for (int off = 32; off; off >>= 1) {
        s1 += __shfl_down(s1, off, 64);
        s2 += __shfl_down(s2, off, 64);
    }
    float mu   = __shfl(s1, 0, 64) * (1.0f / DE_DIM);
    float var  = __shfl(s2, 0, 64) * (1.0f / DE_DIM) - mu * mu;
    float rstd = rsqrtf(var + 1e-5f);
    float* orow = dn + (size_t)r * DE_DIM;
    for (int i = lane; i < DE_DIM; i += 64)
        orow[i] = (row[i] - mu) * rstd * ln_g[i] + ln_b[i];
}

// ---------------- kernel C1: K-split QKV GEMM partials ---------------------
// grid (BATCH/4, 3 matrices, KS slices). Each block: 4 rows x 64 cols over a
// K-slice of 186, dn slice staged in LDS, 6 independent acc chains.
__global__ __launch_bounds__(256) void qkv_partial(
    const float* __restrict__ dn,
    const float* __restrict__ qW, const float* __restrict__ kW,
    const float* __restrict__ vW, float* __restrict__ part) {
    int rt = blockIdx.x;
    int m  = blockIdx.y;
    int ks = blockIdx.z;
    __shared__ float dl[4][KLEN];
    int tid = threadIdx.x, w = tid >> 6, col = tid & 63;
    for (int i = tid; i < 4 * KLEN; i += 256) {
        int rr = i / KLEN, ii = i - rr * KLEN;
        dl[rr][ii] = dn[(size_t)(rt * 4 + rr) * DE_DIM + ks * KLEN + ii];
    }
    __syncthreads();
    const float* Wm = ((m == 0) ? qW : (m == 1) ? kW : vW) + (size_t)ks * KLEN * 64;
    float a[6] = {0, 0, 0, 0, 0, 0};
    for (int i = 0; i < KLEN; i += 6) {       // 186 = 31*6
        #pragma unroll
        for (int j = 0; j < 6; ++j)
            a[j] += dl[w][i + j] * Wm[(size_t)(i + j) * 64 + col];
    }
    float acc = ((a[0] + a[1]) + (a[2] + a[3])) + (a[4] + a[5]);
    part[(((size_t)m * KS + ks) * BATCH + rt * 4 + w) * 64 + col] = acc;
}

// ---------------- kernel C1b: reduce partials + bias ------------------------
__global__ __launch_bounds__(256) void qkv_reduce(
    const float* __restrict__ part,
    const float* __restrict__ qb, const float* __restrict__ kb,
    const float* __restrict__ vb,
    float* __restrict__ Q, float* __restrict__ K, float* __restrict__ V) {
    int idx = blockIdx.x * 256 + threadIdx.x;   // 0 .. 3*512*64-1
    int m  = idx >> 15;                         // BATCH*64 = 32768
    int rc = idx & 32767;
    float s = 0.f;
    #pragma unroll
    for (int ks = 0; ks < KS; ++ks)
        s += part[((size_t)m * KS + ks) * (BATCH * 64) + rc];
    const float* bm = (m == 0) ? qb : (m == 1) ? kb : vb;
    s += bm[rc & 63];
    float* Om = (m == 0) ? Q : (m == 1) ? K : V;
    Om[rc] = s;
}

// ---------------- fallback C1 (used only if ws too small) ------------------
__global__ __launch_bounds__(256) void qkv_fused(
    const float* __restrict__ de, const float* __restrict__ ln_g,
    const float* __restrict__ ln_b,
    const float* __restrict__ qW, const float* __restrict__ qb,
    const float* __restrict__ kW, const float* __restrict__ kb,
    const float* __restrict__ vW, const float* __restrict__ vb,
    float* __restrict__ Q, float* __restrict__ K, float* __restrict__ V) {
    int r0 = blockIdx.x * 4;
    int m  = blockIdx.y;
    __shared__ float dn[4][DE_DIM];
    int tid  = threadIdx.x;
    int w    = tid >> 6;
    int lane = tid & 63;
    const float* row = de + (size_t)(r0 + w) * DE_DIM;
    float s1 = 0.f, s2 = 0.f;
    for (int i = lane; i < DE_DIM; i += 64) {
        float v = row[i]; dn[w][i] = v; s1 += v; s2 += v * v;
    }
    #pragma unroll
    for (int off = 32; off; off >>= 1) {
        s1 += __shfl_down(s1, off, 64);
        s2 += __shfl_down(s2, off, 64);
    }
    float mu   = __shfl(s1, 0, 64) * (1.0f / DE_DIM);
    float var  = __shfl(s2, 0, 64) * (1.0f / DE_DIM) - mu * mu;
    float rstd = rsqrtf(var + 1e-5f);
    for (int i = lane; i < DE_DIM; i += 64)
        dn[w][i] = (dn[w][i] - mu) * rstd * ln_g[i] + ln_b[i];
    __syncthreads();
    const float* Wm = (m == 0) ? qW : (m == 1) ? kW : vW;
    const float* bm = (m == 0) ? qb : (m == 1) ? kb : vb;
    float*       Om = (m == 0) ? Q  : (m == 1) ? K  : V;
    float a[10];
    #pragma unroll
    for (int j = 0; j < 10; ++j) a[j] = 0.f;
    for (int i = 0; i < DE_DIM; i += 10) {
        #pragma unroll
        for (int j = 0; j < 10; ++j)
            a[j] += dn[w][i + j] * Wm[(size_t)(i + j) * 64 + (tid & 63)];
    }
    float acc = (((a[0] + a[1]) + (a[2] + a[3])) + ((a[4] + a[5]) + (a[6] + a[7])))
              + (a[8] + a[9]) + bm[tid & 63];
    Om[(size_t)(r0 + w) * 64 + (tid & 63)] = acc;
}

// ---------------- kernel C2: attention + fusion tail -----------------------
__global__ __launch_bounds__(256) void attn_final(
    const float* __restrict__ Q, const float* __restrict__ K,
    const float* __restrict__ V, const float* __restrict__ pooled,
    const float* __restrict__ fgW, const float* __restrict__ fgb,
    const float* __restrict__ faW, const float* __restrict__ fab,
    float* __restrict__ out) {
    int b = blockIdx.x;
    int tid = threadIdx.x;
    __shared__ float qrow[64];
    __shared__ float p[BATCH];
    __shared__ float red[8];
    __shared__ float pv[4][64];
    __shared__ float xde[64], xout[64];
    if (tid < 64) qrow[tid] = Q[(size_t)b * 64 + tid];
    __syncthreads();

    float sj[2];
    #pragma unroll
    for (int r = 0; r < 2; ++r) {
        int j = tid + r * 256;
        const float4* k4 = (const float4*)(K + (size_t)j * 64);
        float a = 0.f;
        #pragma unroll
        for (int i = 0; i < 16; ++i) {
            float4 kv = k4[i];
            a += qrow[4*i]   * kv.x + qrow[4*i+1] * kv.y
               + qrow[4*i+2] * kv.z + qrow[4*i+3] * kv.w;
        }
        sj[r] = a * 0.125f;
    }
    float mx = fmaxf(sj[0], sj[1]);
    for (int off = 32; off; off >>= 1) mx = fmaxf(mx, __shfl_down(mx, off, 64));
    if ((tid & 63) == 0) red[tid >> 6] = mx;
    __syncthreads();
    mx = fmaxf(fmaxf(red[0], red[1]), fmaxf(red[2], red[3]));
    float e0 = __expf(sj[0] - mx), e1 = __expf(sj[1] - mx);
    p[tid] = e0; p[tid + 256] = e1;
    float s = e0 + e1;
    for (int off = 32; off; off >>= 1) s += __shfl_down(s, off, 64);
    if ((tid & 63) == 0) red[4 + (tid >> 6)] = s;
    __syncthreads();
    float denom = red[4] + red[5] + red[6] + red[7];

    int o = tid & 63, cq = tid >> 6;
    float acc = 0.f;
    #pragma unroll 4
    for (int j = cq * 128; j < cq * 128 + 128; ++j)
        acc += p[j] * V[(size_t)j * 64 + o];
    pv[cq][o] = acc;
    __syncthreads();
    if (tid < 64)
        xde[tid] = (pv[0][tid] + pv[1][tid] + pv[2][tid] + pv[3][tid]) / denom;
    if (tid >= 64 && tid < 128) {
        int oo = tid - 64;
        float a = fgb[oo];
        #pragma unroll
        for (int j = 0; j < NBANDS * NC; ++j) {
            int band = j / NC, c = j % NC;
            a += pooled[((size_t)band * BATCH + b) * NC + c] * fgW[j * 64 + oo];
        }
        xout[oo] = eluf(a);
    }
    __syncthreads();
    if (tid < NC) {
        float a = fab[tid];
        for (int i = 0; i < 64; ++i) a += xout[i] * faW[i * NC + tid];
        for (int i = 0; i < 64; ++i) a += xde[i] * faW[(64 + i) * NC + tid];
        out[(size_t)b * NC + tid] = eluf(a);
    }
}

extern "C" void kernel_launch(void* const* d_in, const int* in_sizes, int n_in,
                              void* d_out, int out_size, void* d_ws, size_t ws_size,
                              hipStream_t stream) {
    const float* x     = (const float*)d_in[0];
    const int*   ei    = (const int*)  d_in[1];
    const float* de    = (const float*)d_in[3];
    const float* bn_g  = (const float*)d_in[4];
    const float* bn_b  = (const float*)d_in[5];
    const float* W     = (const float*)d_in[6];
    const float* attS  = (const float*)d_in[7];
    const float* attD  = (const float*)d_in[8];
    const float* gbias = (const float*)d_in[9];
    const float* fgW   = (const float*)d_in[10];
    const float* fgb   = (const float*)d_in[11];
    const float* ln_g  = (const float*)d_in[12];
    const float* ln_b  = (const float*)d_in[13];
    const float* qW    = (const float*)d_in[14];
    const float* qb    = (const float*)d_in[15];
    const float* kW    = (const float*)d_in[16];
    const float* kb    = (const float*)d_in[17];
    const float* vW    = (const float*)d_in[18];
    const float* vb    = (const float*)d_in[19];
    const float* faW   = (const float*)d_in[20];
    const float* fab   = (const float*)d_in[21];
    float* ws  = (float*)d_ws;
    float* out = (float*)d_out;

    hipMemsetAsync(d_ws, 0, 64 * sizeof(float), stream);
    bn_stats<<<dim3(NBANDS, 8), 256, 0, stream>>>(x, ws + WS_BN);
    gat_kernel<<<dim3(BATCH, NBANDS), 256, 0, stream>>>(
        x, ei, bn_g, bn_b, W, attS, attD, gbias, ws + WS_BN, ws + WS_POOLED);

    if (ws_size >= (size_t)WS_END * sizeof(float)) {
        ln_kernel<<<BATCH / 4, 256, 0, stream>>>(de, ln_g, ln_b, ws + WS_DN);
        qkv_partial<<<dim3(BATCH / 4, 3, KS), 256, 0, stream>>>(
            ws + WS_DN, qW, kW, vW, ws + WS_PART);
        qkv_reduce<<<(3 * BATCH * 64) / 256, 256, 0, stream>>>(
            ws + WS_PART, qb, kb, vb, ws + WS_Q, ws + WS_K, ws + WS_V);
    } else {
        qkv_fused<<<dim3(BATCH / 4, 3), 256, 0, stream>>>(
            de, ln_g, ln_b, qW, qb, kW, kb, vW, vb,
            ws + WS_Q, ws + WS_K, ws + WS_V);
    }
    attn_final<<<BATCH, 256, 0, stream>>>(ws + WS_Q, ws + WS_K, ws + WS_V,
                                          ws + WS_POOLED, fgW, fgb, faW, fab, out);
}

// Round 5
// 74.949 us; speedup vs baseline: 7.4617x; 1.3815x over previous
//
#include <hip/hip_runtime.h>
#include <math.h>

#define NBANDS 5
#define BATCH  512
#define NPG    62
#define NTOT   (BATCH*NPG)     // 31744
#define F_IN   5
#define NH     8
#define NC     3
#define HC     (NH*NC)         // 24
#define EG     (NPG*16)        // 992 edges per graph
#define ETOT   (BATCH*EG)      // 507904
#define EPG    (EG+NPG)        // 1054 incl self loops
#define DE_DIM 930
#define KS     5
#define KLEN   186             // 930/5 = 31*6

// workspace layout (floats) — no zeroing required anywhere
#define WS_BN     0                        // 40 blocks * 10 partials (pad 512)
#define WS_LNS    512                      // 512 rows * {mu, rstd}
#define WS_POOLED 1536                     // 5*512*3 = 7680
#define WS_Q      (WS_POOLED + NBANDS*BATCH*NC)
#define WS_KT     (WS_Q  + BATCH*64)       // K transposed [64][512]
#define WS_V      (WS_KT + BATCH*64)
#define WS_PART   (WS_V  + BATCH*64)       // 3*KS*512*64
#define WS_END    (WS_PART + 3*KS*BATCH*64)

__device__ __forceinline__ float eluf(float x) { return x > 0.f ? x : expm1f(x); }

// ---------- kernel 1: BN chunk partials (blocks 0..39) + LN row stats ------
__global__ __launch_bounds__(256) void stats_kernel(
    const float* __restrict__ x, const float* __restrict__ de,
    float* __restrict__ ws) {
    int bid = blockIdx.x;
    int tid = threadIdx.x;
    int w = tid >> 6, lane = tid & 63;
    if (bid < 40) {                         // BN: band = bid/8, chunk = bid%8
        int band = bid >> 3, chunk = bid & 7;
        const int ROWS = NTOT / 8;          // 3968
        int r0 = chunk * ROWS;
        const float* xb = x + (size_t)band * NTOT * F_IN;
        float s[F_IN] = {0,0,0,0,0}, q[F_IN] = {0,0,0,0,0};
        for (int r = r0 + tid; r < r0 + ROWS; r += 256) {
            const float* row = xb + (size_t)r * F_IN;
            #pragma unroll
            for (int f = 0; f < F_IN; ++f) { float v = row[f]; s[f] += v; q[f] += v * v; }
        }
        #pragma unroll
        for (int f = 0; f < F_IN; ++f) {
            for (int off = 32; off; off >>= 1) {
                s[f] += __shfl_down(s[f], off, 64);
                q[f] += __shfl_down(q[f], off, 64);
            }
        }
        __shared__ float part[4][10];
        if (lane == 0) {
            #pragma unroll
            for (int f = 0; f < F_IN; ++f) { part[w][f] = s[f]; part[w][5 + f] = q[f]; }
        }
        __syncthreads();
        if (tid < 10) {
            float t = part[0][tid] + part[1][tid] + part[2][tid] + part[3][tid];
            ws[WS_BN + (band * 8 + chunk) * 10 + tid] = t;
        }
    } else {                                // LN stats: 4 rows per block
        int r = (bid - 40) * 4 + w;
        const float* row = de + (size_t)r * DE_DIM;
        float s1 = 0.f, s2 = 0.f;
        for (int i = lane; i < DE_DIM; i += 64) { float v = row[i]; s1 += v; s2 += v * v; }
        #pragma unroll
        for (int off = 32; off; off >>= 1) {
            s1 += __shfl_down(s1, off, 64);
            s2 += __shfl_down(s2, off, 64);
        }
        if (lane == 0) {
            float mu  = s1 * (1.0f / DE_DIM);
            float var = s2 * (1.0f / DE_DIM) - mu * mu;
            ws[WS_LNS + r * 2]     = mu;
            ws[WS_LNS + r * 2 + 1] = rsqrtf(var + 1e-5f);
        }
    }
}

// ---------------- kernel 2: per-(band,graph) GAT + mean pool ---------------
__global__ __launch_bounds__(256) void gat_kernel(
    const float* __restrict__ x, const int* __restrict__ ei,
    const float* __restrict__ bn_g, const float* __restrict__ bn_b,
    const float* __restrict__ Wg, const float* __restrict__ attSg,
    const float* __restrict__ attDg, const float* __restrict__ biasg,
    const float* __restrict__ wsbn, float* __restrict__ pooled) {
    int g    = blockIdx.x;
    int band = blockIdx.y;
    __shared__ float Wl[F_IN * HC];
    __shared__ float attS[HC], attD[HC];
    __shared__ float bnsum[10];
    __shared__ float scale[F_IN], shift[F_IN];
    __shared__ float xns[NPG * F_IN];
    __shared__ float xt[NPG * HC];
    __shared__ float als[NPG * NH], ald[NPG * NH];
    __shared__ int   deg[NPG];
    __shared__ int   offs[NPG + 1];
    __shared__ int   cur[NPG];
    __shared__ int   csr[EPG];
    __shared__ float outd[NPG][NC];

    int tid = threadIdx.x;
    int lane = tid & 63;
    int nbase = g * NPG;

    // P1: constants + bn partial reduce + deg init
    if (tid < F_IN * HC) Wl[tid] = Wg[band * F_IN * HC + tid];
    if (tid >= 128 && tid < 128 + HC) attS[tid - 128] = attSg[band * HC + tid - 128];
    if (tid >= 160 && tid < 160 + HC) attD[tid - 160] = attDg[band * HC + tid - 160];
    if (tid < NPG) deg[tid] = 0;
    if (tid >= 192 && tid < 202) {
        int f = tid - 192;
        float t = 0.f;
        #pragma unroll
        for (int c = 0; c < 8; ++c) t += wsbn[(band * 8 + c) * 10 + f];
        bnsum[f] = t;
    }
    __syncthreads();

    const int* srcp = ei + (size_t)band * 2 * ETOT + (size_t)g * EG;
    const int* dstp = srcp + ETOT;

    // P2: degree count + BN scale/shift
    for (int e = tid; e < EG; e += 256) atomicAdd(&deg[dstp[e] - nbase], 1);
    if (tid < F_IN) {
        float mu  = bnsum[tid] * (1.0f / NTOT);
        float var = bnsum[5 + tid] * (1.0f / NTOT) - mu * mu;
        float sc  = rsqrtf(var + 1e-5f) * bn_g[band * F_IN + tid];
        scale[tid] = sc;
        shift[tid] = bn_b[band * F_IN + tid] - mu * sc;
    }
    __syncthreads();

    // P3: normalized features (310 contiguous) + wave1 exclusive scan of deg
    {
        const float* xr = x + (size_t)band * NTOT * F_IN + (size_t)nbase * F_IN;
        for (int i = tid; i < NPG * F_IN; i += 256) {
            int f = i % F_IN;
            xns[i] = xr[i] * scale[f] + shift[f];
        }
    }
    if (tid >= 64 && tid < 128) {
        int l = lane;
        int dv = (l < NPG) ? deg[l] + 1 : 0;     // +1 self loop
        int sc = dv;
        #pragma unroll
        for (int off = 1; off < 64; off <<= 1) {
            int t = __shfl_up(sc, off, 64);
            if (l >= off) sc += t;
        }
        if (l < NPG) offs[l + 1] = sc;
        if (l == 0)  offs[0] = 0;
    }
    __syncthreads();

    // P4: xt = xns @ W ; self-loop slot + cur init
    for (int p = tid; p < NPG * HC; p += 256) {
        int n = p / HC, o = p - n * HC;
        float a = 0.f;
        #pragma unroll
        for (int f = 0; f < F_IN; ++f) a += xns[n * F_IN + f] * Wl[f * HC + o];
        xt[p] = a;
    }
    if (tid < NPG) { int o0 = offs[tid]; csr[o0] = tid; cur[tid] = o0 + 1; }
    __syncthreads();

    // P5: attention logits + CSR scatter
    for (int p = tid; p < NPG * NH; p += 256) {
        int n = p >> 3, h = p & 7;
        float as = 0.f, ad = 0.f;
        #pragma unroll
        for (int c = 0; c < NC; ++c) {
            float v = xt[n * HC + h * NC + c];
            as += v * attS[h * NC + c];
            ad += v * attD[h * NC + c];
        }
        als[p] = as;
        ald[p] = ad;
    }
    for (int e = tid; e < EG; e += 256) {
        int ld = dstp[e] - nbase;
        int p = atomicAdd(&cur[ld], 1);
        csr[p] = srcp[e] - nbase;
    }
    __syncthreads();

    // P6: gather — one (dst,head) per thread, single-pass softmax
    for (int p = tid; p < NPG * NH; p += 256) {
        int d = p >> 3, h = p & 7;
        int s0 = offs[d], s1 = offs[d + 1];
        float adv = ald[p];
        float den = 0.f, m0 = 0.f, m1 = 0.f, m2 = 0.f;
        for (int e = s0; e < s1; ++e) {
            int s = csr[e];
            float v = als[s * NH + h] + adv;
            v = v > 0.f ? v : 0.2f * v;
            float ex = __expf(v);
            den += ex;
            m0 += ex * xt[s * HC + h * NC + 0];
            m1 += ex * xt[s * HC + h * NC + 1];
            m2 += ex * xt[s * HC + h * NC + 2];
        }
        float rd = 1.0f / den;
        float o0 = m0 * rd, o1 = m1 * rd, o2 = m2 * rd;
        #pragma unroll
        for (int off = 1; off < 8; off <<= 1) {   // head sum within 8-lane group
            o0 += __shfl_xor(o0, off, 64);
            o1 += __shfl_xor(o1, off, 64);
            o2 += __shfl_xor(o2, off, 64);
        }
        if (h == 0) { outd[d][0] = o0; outd[d][1] = o1; outd[d][2] = o2; }
    }
    __syncthreads();

    // P7: elu(head mean + bias) then graph mean pool
    float oc[NC] = {0.f, 0.f, 0.f};
    if (tid < NPG) {
        #pragma unroll
        for (int c = 0; c < NC; ++c)
            oc[c] = eluf(outd[tid][c] * (1.0f / NH) + biasg[band * NC + c]);
    }
    if (tid < 64) {
        #pragma unroll
        for (int c = 0; c < NC; ++c) {
            float v = oc[c];
            for (int off = 32; off; off >>= 1) v += __shfl_down(v, off, 64);
            if (tid == 0)
                pooled[((size_t)band * BATCH + g) * NC + c] = v * (1.0f / NPG);
        }
    }
}

// ---------- kernel 3: K-split QKV GEMM partials with inline LayerNorm ------
__global__ __launch_bounds__(256) void qkv_partial(
    const float* __restrict__ de, const float* __restrict__ lns,
    const float* __restrict__ ln_g, const float* __restrict__ ln_b,
    const float* __restrict__ qW, const float* __restrict__ kW,
    const float* __restrict__ vW, float* __restrict__ part) {
    int rt = blockIdx.x;
    int m  = blockIdx.y;
    int ks = blockIdx.z;
    __shared__ float dl[4][KLEN];
    int tid = threadIdx.x, w = tid >> 6, col = tid & 63;
    for (int i = tid; i < 4 * KLEN; i += 256) {
        int rr = i / KLEN, ii = i - rr * KLEN;
        int row = rt * 4 + rr, gcol = ks * KLEN + ii;
        float mu = lns[row * 2], rstd = lns[row * 2 + 1];
        dl[rr][ii] = (de[(size_t)row * DE_DIM + gcol] - mu) * rstd * ln_g[gcol] + ln_b[gcol];
    }
    __syncthreads();
    const float* Wm = ((m == 0) ? qW : (m == 1) ? kW : vW) + (size_t)ks * KLEN * 64;
    float a[6] = {0, 0, 0, 0, 0, 0};
    for (int i = 0; i < KLEN; i += 6) {       // 186 = 31*6
        #pragma unroll
        for (int j = 0; j < 6; ++j)
            a[j] += dl[w][i + j] * Wm[(size_t)(i + j) * 64 + col];
    }
    float acc = ((a[0] + a[1]) + (a[2] + a[3])) + (a[4] + a[5]);
    part[(((size_t)m * KS + ks) * BATCH + rt * 4 + w) * 64 + col] = acc;
}

// ---------- kernel 4: reduce partials + bias; K is emitted transposed ------
__global__ __launch_bounds__(256) void qkv_reduce(
    const float* __restrict__ part,
    const float* __restrict__ qb, const float* __restrict__ kb,
    const float* __restrict__ vb,
    float* __restrict__ Q, float* __restrict__ KT, float* __restrict__ V) {
    int idx = blockIdx.x * 256 + threadIdx.x;   // 0 .. 3*512*64-1
    int m  = idx >> 15;                         // BATCH*64 = 32768
    int local = idx & 32767;
    if (m == 1) {                               // K -> KT[64][512], coalesced store
        int row = local & 511, col = local >> 9;
        float s = 0.f;
        #pragma unroll
        for (int ks = 0; ks < KS; ++ks)
            s += part[(((size_t)KS + ks) << 15) + (row << 6) + col];
        KT[local] = s + kb[col];                // local == col*512 + row
    } else {
        int col = local & 63;
        float s = 0.f;
        #pragma unroll
        for (int ks = 0; ks < KS; ++ks)
            s += part[(((size_t)m * KS + ks) << 15) + local];
        s += (m == 0) ? qb[col] : vb[col];
        ((m == 0) ? Q : V)[local] = s;
    }
}

// ---------------- fallback (ws too small): fused LN+QKV --------------------
__global__ __launch_bounds__(256) void qkv_fused_fb(
    const float* __restrict__ de, const float* __restrict__ ln_g,
    const float* __restrict__ ln_b,
    const float* __restrict__ qW, const float* __restrict__ qb,
    const float* __restrict__ kW, const float* __restrict__ kb,
    const float* __restrict__ vW, const float* __restrict__ vb,
    float* __restrict__ Q, float* __restrict__ KT, float* __restrict__ V) {
    int r0 = blockIdx.x * 4;
    int m  = blockIdx.y;
    __shared__ float dn[4][DE_DIM];
    int tid  = threadIdx.x;
    int w    = tid >> 6, lane = tid & 63;
    const float* row = de + (size_t)(r0 + w) * DE_DIM;
    float s1 = 0.f, s2 = 0.f;
    for (int i = lane; i < DE_DIM; i += 64) {
        float v = row[i]; dn[w][i] = v; s1 += v; s2 += v * v;
    }
    #pragma unroll
    for (int off = 32; off; off >>= 1) {
        s1 += __shfl_down(s1, off, 64);
        s2 += __shfl_down(s2, off, 64);
    }
    float mu   = __shfl(s1, 0, 64) * (1.0f / DE_DIM);
    float var  = __shfl(s2, 0, 64) * (1.0f / DE_DIM) - mu * mu;
    float rstd = rsqrtf(var + 1e-5f);
    for (int i = lane; i < DE_DIM; i += 64)
        dn[w][i] = (dn[w][i] - mu) * rstd * ln_g[i] + ln_b[i];
    __syncthreads();
    const float* Wm = (m == 0) ? qW : (m == 1) ? kW : vW;
    const float* bm = (m == 0) ? qb : (m == 1) ? kb : vb;
    float a[10];
    #pragma unroll
    for (int j = 0; j < 10; ++j) a[j] = 0.f;
    for (int i = 0; i < DE_DIM; i += 10) {
        #pragma unroll
        for (int j = 0; j < 10; ++j)
            a[j] += dn[w][i + j] * Wm[(size_t)(i + j) * 64 + lane];
    }
    float acc = (((a[0] + a[1]) + (a[2] + a[3])) + ((a[4] + a[5]) + (a[6] + a[7])))
              + (a[8] + a[9]) + bm[lane];
    int r = r0 + w;
    if (m == 1) KT[lane * BATCH + r] = acc;
    else ((m == 0) ? Q : V)[(size_t)r * 64 + lane] = acc;
}

// ---------------- kernel 5: attention + fusion tail ------------------------
__global__ __launch_bounds__(256) void attn_final(
    const float* __restrict__ Q, const float* __restrict__ KT,
    const float* __restrict__ V, const float* __restrict__ pooled,
    const float* __restrict__ fgW, const float* __restrict__ fgb,
    const float* __restrict__ faW, const float* __restrict__ fab,
    float* __restrict__ out) {
    int b = blockIdx.x;
    int tid = threadIdx.x;
    __shared__ float qrow[64];
    __shared__ float p[BATCH];
    __shared__ float red[8];
    __shared__ float pv[4][64];
    __shared__ float xde[64], xout[64];
    if (tid < 64) qrow[tid] = Q[(size_t)b * 64 + tid];
    __syncthreads();

    // scores: fully-coalesced KT reads (lane j reads KT[i][j])
    float a0 = 0.f, a1 = 0.f, b0 = 0.f, b1 = 0.f;
    #pragma unroll 8
    for (int i = 0; i < 64; i += 2) {
        float q0 = qrow[i], q1 = qrow[i + 1];
        a0 += q0 * KT[(size_t)i * BATCH + tid];
        a1 += q1 * KT[(size_t)(i + 1) * BATCH + tid];
        b0 += q0 * KT[(size_t)i * BATCH + tid + 256];
        b1 += q1 * KT[(size_t)(i + 1) * BATCH + tid + 256];
    }
    float sj0 = (a0 + a1) * 0.125f, sj1 = (b0 + b1) * 0.125f;

    float mx = fmaxf(sj0, sj1);
    for (int off = 32; off; off >>= 1) mx = fmaxf(mx, __shfl_down(mx, off, 64));
    if ((tid & 63) == 0) red[tid >> 6] = mx;
    __syncthreads();
    mx = fmaxf(fmaxf(red[0], red[1]), fmaxf(red[2], red[3]));
    float e0 = __expf(sj0 - mx), e1 = __expf(sj1 - mx);
    p[tid] = e0; p[tid + 256] = e1;
    float s = e0 + e1;
    for (int off = 32; off; off >>= 1) s += __shfl_down(s, off, 64);
    if ((tid & 63) == 0) red[4 + (tid >> 6)] = s;
    __syncthreads();
    float denom = red[4] + red[5] + red[6] + red[7];

    int o = tid & 63, cq = tid >> 6;
    float acc = 0.f;
    #pragma unroll 4
    for (int j = cq * 128; j < cq * 128 + 128; ++j)
        acc += p[j] * V[(size_t)j * 64 + o];
    pv[cq][o] = acc;
    __syncthreads();
    if (tid < 64)
        xde[tid] = (pv[0][tid] + pv[1][tid] + pv[2][tid] + pv[3][tid]) / denom;
    if (tid >= 64 && tid < 128) {
        int oo = tid - 64;
        float a = fgb[oo];
        #pragma unroll
        for (int j = 0; j < NBANDS * NC; ++j) {
            int band = j / NC, c = j % NC;
            a += pooled[((size_t)band * BATCH + b) * NC + c] * fgW[j * 64 + oo];
        }
        xout[oo] = eluf(a);
    }
    __syncthreads();
    if (tid < NC) {
        float a = fab[tid];
        for (int i = 0; i < 64; ++i) a += xout[i] * faW[i * NC + tid];
        for (int i = 0; i < 64; ++i) a += xde[i] * faW[(64 + i) * NC + tid];
        out[(size_t)b * NC + tid] = eluf(a);
    }
}

extern "C" void kernel_launch(void* const* d_in, const int* in_sizes, int n_in,
                              void* d_out, int out_size, void* d_ws, size_t ws_size,
                              hipStream_t stream) {
    const float* x     = (const float*)d_in[0];
    const int*   ei    = (const int*)  d_in[1];
    const float* de    = (const float*)d_in[3];
    const float* bn_g  = (const float*)d_in[4];
    const float* bn_b  = (const float*)d_in[5];
    const float* W     = (const float*)d_in[6];
    const float* attS  = (const float*)d_in[7];
    const float* attD  = (const float*)d_in[8];
    const float* gbias = (const float*)d_in[9];
    const float* fgW   = (const float*)d_in[10];
    const float* fgb   = (const float*)d_in[11];
    const float* ln_g  = (const float*)d_in[12];
    const float* ln_b  = (const float*)d_in[13];
    const float* qW    = (const float*)d_in[14];
    const float* qb    = (const float*)d_in[15];
    const float* kW    = (const float*)d_in[16];
    const float* kb    = (const float*)d_in[17];
    const float* vW    = (const float*)d_in[18];
    const float* vb    = (const float*)d_in[19];
    const float* faW   = (const float*)d_in[20];
    const float* fab   = (const float*)d_in[21];
    float* ws  = (float*)d_ws;
    float* out = (float*)d_out;

    stats_kernel<<<168, 256, 0, stream>>>(x, de, ws);
    gat_kernel<<<dim3(BATCH, NBANDS), 256, 0, stream>>>(
        x, ei, bn_g, bn_b, W, attS, attD, gbias, ws + WS_BN, ws + WS_POOLED);

    if (ws_size >= (size_t)WS_END * sizeof(float)) {
        qkv_partial<<<dim3(BATCH / 4, 3, KS), 256, 0, stream>>>(
            de, ws + WS_LNS, ln_g, ln_b, qW, kW, vW, ws + WS_PART);
        qkv_reduce<<<(3 * BATCH * 64) / 256, 256, 0, stream>>>(
            ws + WS_PART, qb, kb, vb, ws + WS_Q, ws + WS_KT, ws + WS_V);
    } else {
        qkv_fused_fb<<<dim3(BATCH / 4, 3), 256, 0, stream>>>(
            de, ln_g, ln_b, qW, qb, kW, kb, vW, vb,
            ws + WS_Q, ws + WS_KT, ws + WS_V);
    }
    attn_final<<<BATCH, 256, 0, stream>>>(ws + WS_Q, ws + WS_KT, ws + WS_V,
                                          ws + WS_POOLED, fgW, fgb, faW, fab, out);
}